// Round 10
// baseline (141.252 us; speedup 1.0000x reference)
//
#include <hip/hip_runtime.h>
#include <hip/hip_bf16.h>
#include <math.h>

#define D_DIM 192
#define H_DIM 224
#define W_DIM 192
// Output tile per block: IT x JT x KT voxels, 256 threads, 4 voxels/thread.
#define IT 8
#define JT 8
#define KT 16
#define BLOCK 256
#define NUM_XCD 8
// LDS box capacity: up to 256 (i,j)-rows of NKP k-samples.
#define NKP 24
#define MAXROWS 256

// ---------------------------------------------------------------------------
// Kernel 1: compose the 4x4 transform on-device (single thread).
// ---------------------------------------------------------------------------

__device__ inline void mm4(const float* A, const float* B, float* C) {
    for (int r = 0; r < 4; ++r)
        for (int c = 0; c < 4; ++c) {
            float s = 0.f;
            for (int t = 0; t < 4; ++t) s += A[r * 4 + t] * B[t * 4 + c];
            C[r * 4 + c] = s;
        }
}

__device__ inline void inv4(const float* Ain, float* out) {
    float a[4][8];
    for (int r = 0; r < 4; ++r) {
        for (int c = 0; c < 4; ++c) a[r][c] = Ain[r * 4 + c];
        for (int c = 0; c < 4; ++c) a[r][4 + c] = (r == c) ? 1.f : 0.f;
    }
    for (int col = 0; col < 4; ++col) {
        int piv = col;
        float best = fabsf(a[col][col]);
        for (int r = col + 1; r < 4; ++r) {
            float v = fabsf(a[r][col]);
            if (v > best) { best = v; piv = r; }
        }
        if (piv != col) {
            for (int c = 0; c < 8; ++c) {
                float t = a[col][c]; a[col][c] = a[piv][c]; a[piv][c] = t;
            }
        }
        float inv = 1.f / a[col][col];
        for (int c = 0; c < 8; ++c) a[col][c] *= inv;
        for (int r = 0; r < 4; ++r) {
            if (r == col) continue;
            float f = a[r][col];
            for (int c = 0; c < 8; ++c) a[r][c] -= f * a[col][c];
        }
    }
    for (int r = 0; r < 4; ++r)
        for (int c = 0; c < 4; ++c) out[r * 4 + c] = a[r][4 + c];
}

__global__ void compute_T_kernel(const float* __restrict__ ang,
                                 const float* __restrict__ tr,
                                 const float* __restrict__ scl,
                                 const float* __restrict__ ref_v2r,
                                 const float* __restrict__ flo_v2r,
                                 float* __restrict__ Tout) {
    if (threadIdx.x != 0 || blockIdx.x != 0) return;

    const float cogx = 96.f, cogy = 112.f, cogz = 96.f;

    float cx = cosf(ang[0]), sx = sinf(ang[0]);
    float cy = cosf(ang[1]), sy = sinf(ang[1]);
    float cz = cosf(ang[2]), sz = sinf(ang[2]);

    float Rx[9] = {1, 0, 0, 0, cx, -sx, 0, sx, cx};
    float Ry[9] = {cy, 0, sy, 0, 1, 0, -sy, 0, cy};
    float Rz[9] = {cz, -sz, 0, sz, cz, 0, 0, 0, 1};
    float Ryz[9], R[9];
    for (int r = 0; r < 3; ++r)
        for (int c = 0; c < 3; ++c) {
            float s = 0.f;
            for (int t = 0; t < 3; ++t) s += Ry[r * 3 + t] * Rz[t * 3 + c];
            Ryz[r * 3 + c] = s;
        }
    for (int r = 0; r < 3; ++r)
        for (int c = 0; c < 3; ++c) {
            float s = 0.f;
            for (int t = 0; t < 3; ++t) s += Rx[r * 3 + t] * Ryz[t * 3 + c];
            R[r * 3 + c] = s;
        }

    float s0 = expf(scl[0]), s1 = expf(scl[1]), s2 = expf(scl[2]);

    float Tc[16]   = {1,0,0,-cogx, 0,1,0,-cogy, 0,0,1,-cogz, 0,0,0,1};
    float Tci[16]  = {1,0,0, cogx, 0,1,0, cogy, 0,0,1, cogz, 0,0,0,1};
    float Tsc[16]  = {s0,0,0,0, 0,s1,0,0, 0,0,s2,0, 0,0,0,1};
    float Ttr[16]  = {1,0,0,tr[0], 0,1,0,tr[1], 0,0,1,tr[2], 0,0,0,1};
    float Trot[16] = {R[0],R[1],R[2],0, R[3],R[4],R[5],0, R[6],R[7],R[8],0, 0,0,0,1};

    float m1[16], m2[16], m3[16], Trig[16];
    mm4(Tci, Ttr, m1);
    mm4(m1, Trot, m2);
    mm4(m2, Tsc, m3);
    mm4(m3, Tc, Trig);

    float floinv[16], m4[16], T[16];
    inv4(flo_v2r, floinv);
    mm4(floinv, Trig, m4);
    mm4(m4, ref_v2r, T);

    for (int q = 0; q < 12; ++q) Tout[q] = T[q];
}

// ---------------------------------------------------------------------------
// Kernel 2: trilinear resample via LDS box staging.
//
// EMPIRICAL LAW (R1/R4/R9): each DIVERGENT vmem wave-inst costs ~30-40 cyc
// (TA/L1 per-lane address processing) and that pipe is the saturated
// bottleneck — NOT latency (R9: +16 prefetch DMA insts => +21.5 us, linear).
// Fix: replace per-voxel gathers with (a) coalesced staging of the block's
// input bounding box into LDS (TA fast path) and (b) LDS reads (separate
// pipe, ~6 cyc) for the 8 corners.
//
// Box: transform is affine => min/max of di/dj/dk over the 8 output-tile
// corners bounds every voxel's coords; +-1 margin absorbs FP reassociation
// differences between corner and voxel evaluation. Staged values are EXACT
// copies of vol => arithmetic identical to the validated path.
// Runtime fit check (nj>=8, nk<=NKP, ni*nj<=MAXROWS) -> else fall back to
// the proven direct-gather path (never taken for the test's small T).
//
// Kept: XCD slab swizzle (R3: FETCH 92->18MB), EXACT R1 coordinate
// expression (R2: reassociation flips the ok-mask), nontemporal stores.
// ---------------------------------------------------------------------------

__global__ __launch_bounds__(BLOCK) void resample_kernel(
    const float* __restrict__ vol,
    const float* __restrict__ T,
    float* __restrict__ out) {

    constexpr int NTI = D_DIM / IT;                 // 24
    constexpr int NTJ = H_DIM / JT;                 // 28
    constexpr int NTK = W_DIM / KT;                 // 12
    constexpr int NBLK = NTI * NTJ * NTK;           // 8064
    constexpr int PER_XCD = NBLK / NUM_XCD;         // 1008

    __shared__ float S[MAXROWS * NKP];              // 24 KB

    // XCD slab swizzle
    const int b = blockIdx.x;
    const int xcd = b & (NUM_XCD - 1);
    const int sb = xcd * PER_XCD + (b >> 3);
    const int it = sb / (NTJ * NTK);
    const int rem = sb - it * (NTJ * NTK);
    const int jt = rem / NTK;
    const int kt = rem - jt * NTK;
    const int ibase = it * IT, jbase = jt * JT, kbase = kt * KT;

    const int tid = threadIdx.x;
    const int kx = tid & 15;
    const int jy = (tid >> 4) & 7;
    const int ig = tid >> 7;                        // 0,1

    const float t00 = T[0],  t01 = T[1],  t02 = T[2],  t03 = T[3];
    const float t10 = T[4],  t11 = T[5],  t12 = T[6],  t13 = T[7];
    const float t20 = T[8],  t21 = T[9],  t22 = T[10], t23 = T[11];

    // ---- Bounding box from the 8 tile corners (block-uniform) ----
    float dil = 1e30f, dih = -1e30f;
    float djl = 1e30f, djh = -1e30f;
    float dkl = 1e30f, dkh = -1e30f;
#pragma unroll
    for (int c = 0; c < 8; ++c) {
        const float ci = (float)(ibase + ((c & 1) ? IT - 1 : 0));
        const float cj = (float)(jbase + ((c & 2) ? JT - 1 : 0));
        const float ck = (float)(kbase + ((c & 4) ? KT - 1 : 0));
        const float di = t00 * ci + t01 * cj + t02 * ck + t03;
        const float dj = t10 * ci + t11 * cj + t12 * ck + t13;
        const float dk = t20 * ci + t21 * cj + t22 * ck + t23;
        dil = fminf(dil, di); dih = fmaxf(dih, di);
        djl = fminf(djl, dj); djh = fmaxf(djh, dj);
        dkl = fminf(dkl, dk); dkh = fmaxf(dkh, dk);
    }
    const int i0b = min(max((int)floorf(dil) - 1, 0), D_DIM - 1);
    const int iHi = min(max((int)floorf(dih) + 2, 0), D_DIM - 1);
    const int j0b = min(max((int)floorf(djl) - 1, 0), H_DIM - 1);
    const int jHi = min(max((int)floorf(djh) + 2, 0), H_DIM - 1);
    const int k0b = min(max((int)floorf(dkl) - 1, 0), W_DIM - 1);
    const int kHi = min(max((int)floorf(dkh) + 2, 0), W_DIM - 1);
    const int ni = iHi - i0b + 1;
    const int nj = jHi - j0b + 1;
    const int nk = kHi - k0b + 1;
    const int R = ni * nj;
    const bool fits = (R <= MAXROWS) && (nk <= NKP) && (nj >= 8);

    // ---- Stage the box into LDS with coalesced loads ----
    if (fits) {
        const int bk = tid & 31;
        const int tr = tid >> 5;                    // 0..7 (< 8 <= nj)
        int r = tr;
        int bj = tr;                                // bi = 0 at start
        int rowg = i0b * H_DIM + (j0b + bj);        // global (i,j)-row id
        const int passes = (R + 7) >> 3;
        for (int p = 0; p < passes; ++p) {
            if (r < R && bk < nk) {
                S[r * NKP + bk] = vol[rowg * W_DIM + k0b + bk];
            }
            r += 8;
            bj += 8; rowg += 8;
            if (bj >= nj) { bj -= nj; rowg += H_DIM - nj; }  // one wrap max (nj>=8)
        }
        __syncthreads();
    }

    // ---- Per-voxel interpolation (identical arithmetic to validated path) ----
    const float fjv = (float)(jbase + jy);
    const float fkv = (float)(kbase + kx);
#pragma unroll
    for (int v = 0; v < 4; ++v) {
        const int iz = v * 2 + ig;
        const float fiv = (float)(ibase + iz);

        // EXACT R1 expression — do not reassociate (ok-mask boundary, R2).
        const float di = t00 * fiv + t01 * fjv + t02 * fkv + t03;
        const float dj = t10 * fiv + t11 * fjv + t12 * fkv + t13;
        const float dk = t20 * fiv + t21 * fjv + t22 * fkv + t23;

        const bool ok = (di > 0.f) & (dj > 0.f) & (dk > 0.f) &
                        (di <= (float)(D_DIM - 1)) &
                        (dj <= (float)(H_DIM - 1)) &
                        (dk <= (float)(W_DIM - 1));

        float ffi = fminf(fmaxf(floorf(di), 0.f), (float)(D_DIM - 1));
        float ffj = fminf(fmaxf(floorf(dj), 0.f), (float)(H_DIM - 1));
        float ffk = fminf(fmaxf(floorf(dk), 0.f), (float)(W_DIM - 1));

        const float wi = di - ffi, wj = dj - ffj, wk = dk - ffk;

        const int i0 = (int)ffi, j0 = (int)ffj, k0 = (int)ffk;
        const int i1 = min(i0 + 1, D_DIM - 1);
        const int j1 = min(j0 + 1, H_DIM - 1);
        const int k1 = min(k0 + 1, W_DIM - 1);

        float c000, c100, c010, c110, c001, c101, c011, c111;
        if (fits) {
            const int a   = ((i0 - i0b) * nj + (j0 - j0b)) * NKP + (k0 - k0b);
            const int rD  = (i1 - i0) * nj * NKP;   // 0 or nj*NKP
            const int cD  = (j1 - j0) * NKP;        // 0 or NKP
            const int dk1 = k1 - k0;                // 0 or 1
            c000 = S[a];            c001 = S[a + dk1];
            c010 = S[a + cD];       c011 = S[a + cD + dk1];
            c100 = S[a + rD];       c101 = S[a + rD + dk1];
            c110 = S[a + rD + cD];  c111 = S[a + rD + cD + dk1];
        } else {
            const int b00 = (i0 * H_DIM + j0) * W_DIM;
            const int b01 = (i0 * H_DIM + j1) * W_DIM;
            const int b10 = (i1 * H_DIM + j0) * W_DIM;
            const int b11 = (i1 * H_DIM + j1) * W_DIM;
            c000 = vol[b00 + k0]; c100 = vol[b10 + k0];
            c010 = vol[b01 + k0]; c110 = vol[b11 + k0];
            c001 = vol[b00 + k1]; c101 = vol[b10 + k1];
            c011 = vol[b01 + k1]; c111 = vol[b11 + k1];
        }

        const float omwi = 1.f - wi, omwj = 1.f - wj, omwk = 1.f - wk;
        const float val = ((c000 * omwi + c100 * wi) * omwj +
                           (c010 * omwi + c110 * wi) * wj) * omwk +
                          ((c001 * omwi + c101 * wi) * omwj +
                           (c011 * omwi + c111 * wi) * wj) * wk;
        const float res = ok ? val : 0.f;
        __builtin_nontemporal_store(
            res, &out[((ibase + iz) * H_DIM + (jbase + jy)) * W_DIM + kbase + kx]);
    }
}

// ---------------------------------------------------------------------------

extern "C" void kernel_launch(void* const* d_in, const int* in_sizes, int n_in,
                              void* d_out, int out_size, void* d_ws, size_t ws_size,
                              hipStream_t stream) {
    const float* image_targ  = (const float*)d_in[0];
    const float* angle       = (const float*)d_in[1];
    const float* translation = (const float*)d_in[2];
    const float* scaling     = (const float*)d_in[3];
    const float* ref_v2r     = (const float*)d_in[4];
    const float* flo_v2r     = (const float*)d_in[5];
    float* out = (float*)d_out;
    float* Tmat = (float*)d_ws;  // 12 floats

    compute_T_kernel<<<1, 1, 0, stream>>>(angle, translation, scaling,
                                          ref_v2r, flo_v2r, Tmat);

    const int nblk = (D_DIM / IT) * (H_DIM / JT) * (W_DIM / KT);  // 8064
    resample_kernel<<<nblk, BLOCK, 0, stream>>>(image_targ, Tmat, out);
}